// Round 5
// baseline (1843.124 us; speedup 1.0000x reference)
//
#include <hip/hip_runtime.h>
#include <math.h>
#include <float.h>

#define BLK 256

// Compile-time-safe scheduling fence: empty asm with memory clobber.
// (Round 3/4 used __builtin_amdgcn_sched_barrier(0) and the container failed
// twice; this is the conservative equivalent for load-hoisting control.)
#define SCHED_FENCE() asm volatile("" ::: "memory")

// ---------------------------------------------------------------------------
// K0: fast exclusive scan of both count arrays. One block, 1024 threads.
// ---------------------------------------------------------------------------
__device__ __forceinline__ void scan_one(const int* __restrict__ cnt, int n,
                                         int* __restrict__ starts, int* wsum)
{
    const int t = threadIdx.x;
    const int chunk = (n + 1023) / 1024;
    const int base = t * chunk;

    int sum = 0;
    for (int k = 0; k < chunk; k++) {
        int idx = base + k;
        if (idx < n) sum += cnt[idx];
    }

    const int lane = t & 63, wid = t >> 6;
    int v = sum;
#pragma unroll
    for (int off = 1; off < 64; off <<= 1) {
        int y = __shfl_up(v, off);
        if (lane >= off) v += y;
    }
    if (lane == 63) wsum[wid] = v;
    __syncthreads();
    if (wid == 0) {
        int w = (lane < 16) ? wsum[lane] : 0;
#pragma unroll
        for (int off = 1; off < 16; off <<= 1) {
            int y = __shfl_up(w, off);
            if (lane >= off) w += y;
        }
        if (lane < 16) wsum[lane] = w;
    }
    __syncthreads();

    int thr_excl = ((wid > 0) ? wsum[wid - 1] : 0) + v - sum;
    int run = thr_excl;
    for (int k = 0; k < chunk; k++) {
        int idx = base + k;
        if (idx < n) { starts[idx] = run; run += cnt[idx]; }
    }
    if (t == 0) starts[n] = wsum[15];
    __syncthreads();
}

__global__ __launch_bounds__(1024) void scan2_kernel(
    const int* __restrict__ dag_cnt, int nd,
    const int* __restrict__ obs_cnt, int no,
    int* __restrict__ dag_starts, int* __restrict__ obs_starts)
{
    __shared__ int wsum[16];
    scan_one(dag_cnt, nd, dag_starts, wsum);
    scan_one(obs_cnt, no, obs_starts, wsum);
}

// ---------------------------------------------------------------------------
// K1: expand segment ids to per-node arrays (one block per segment).
// ---------------------------------------------------------------------------
__global__ __launch_bounds__(128) void expand_ids_kernel(
    const int* __restrict__ dag_starts, int nd,
    const int* __restrict__ obs_starts, int no,
    int* __restrict__ dag_ids, int* __restrict__ obs_ids)
{
    int seg = blockIdx.x;
    if (seg < nd) {
        int s = dag_starts[seg], e = dag_starts[seg + 1];
        for (int i = s + threadIdx.x; i < e; i += 128) dag_ids[i] = seg;
    } else {
        int g = seg - nd;
        int s = obs_starts[g], e = obs_starts[g + 1];
        for (int i = s + threadIdx.x; i < e; i += 128) obs_ids[i] = g;
    }
}

// ---------------------------------------------------------------------------
// K2: per-segment layer-1 partials (dag rows 37..68 no bias; glob rows 69..100 +b1).
// ---------------------------------------------------------------------------
__global__ __launch_bounds__(256) void seg_h1_kernel(
    const float* __restrict__ dag_sum, int nd,
    const float* __restrict__ glob_sum, int no,
    const float* __restrict__ W1, const float* __restrict__ b1,
    float* __restrict__ dag_h1, float* __restrict__ glob_h1)
{
    __shared__ float Wd[32 * 32];
    __shared__ float Wg[32 * 32];
    for (int t = threadIdx.x; t < 32 * 32; t += 256) {
        int k = t / 32, j = t % 32;
        Wd[t] = W1[(size_t)(37 + k) * 32 + j];
        Wg[t] = W1[(size_t)(69 + k) * 32 + j];
    }
    __syncthreads();

    int gid = blockIdx.x * 256 + threadIdx.x;
    int seg = gid / 32;
    int j   = gid % 32;
    if (seg >= nd + no) return;

    const float* srow;
    const float* Wl;
    float acc;
    float* outp;
    if (seg < nd) {
        srow = dag_sum + (size_t)seg * 32;
        Wl = Wd; acc = 0.f;
        outp = dag_h1 + (size_t)seg * 32 + j;
    } else {
        srow = glob_sum + (size_t)(seg - nd) * 32;
        Wl = Wg; acc = b1[j];
        outp = glob_h1 + (size_t)(seg - nd) * 32 + j;
    }
#pragma unroll
    for (int k = 0; k < 32; k++)
        acc = fmaf(srow[k], Wl[k * 32 + j], acc);
    *outp = acc;
}

// ---------------------------------------------------------------------------
// K3 helpers: chunked, fence-separated phases keep VGPR pressure ~100
// (round-2 lesson: full unroll hoists 32 float4 loads -> >128 live -> scratch
// spill, WRITE_SIZE 8MB -> 133MB, 2x regression).
// ---------------------------------------------------------------------------
template <int KB>
__device__ __forceinline__ void emb_step(const float4 ea, const float4 eb,
                                         const float* __restrict__ W1,
                                         float (&h1a)[32], float (&h1b)[32])
{
    const float ca[4] = {ea.x, ea.y, ea.z, ea.w};
    const float cb[4] = {eb.x, eb.y, eb.z, eb.w};
#pragma unroll
    for (int kk = 0; kk < 4; kk++) {
        const float va = ca[kk];
        const float vb = cb[kk];
#pragma unroll
        for (int j = 0; j < 32; j++) {
            const float w = W1[(KB + kk) * 32 + j];
            h1a[j] = fmaf(va, w, h1a[j]);
            h1b[j] = fmaf(vb, w, h1b[j]);
        }
    }
}

template <int Q>
__device__ __forceinline__ void fold2(const float4* __restrict__ dha,
                                      const float4* __restrict__ gha,
                                      const float4* __restrict__ dhb,
                                      const float4* __restrict__ ghb,
                                      float (&h1a)[32], float (&h1b)[32])
{
#pragma unroll
    for (int q = Q; q < Q + 2; q++) {
        float4 da = dha[q], ga = gha[q];
        float4 db = dhb[q], gb = ghb[q];
        h1a[4 * q + 0] += da.x + ga.x;
        h1a[4 * q + 1] += da.y + ga.y;
        h1a[4 * q + 2] += da.z + ga.z;
        h1a[4 * q + 3] += da.w + ga.w;
        h1b[4 * q + 0] += db.x + gb.x;
        h1b[4 * q + 1] += db.y + gb.y;
        h1b[4 * q + 2] += db.z + gb.z;
        h1b[4 * q + 3] += db.w + gb.w;
    }
}

// ---------------------------------------------------------------------------
// K3: main MLP. TWO nodes per thread (i, i+BLK) in one interleaved FMA stream
// so every scalar-loaded weight (SGPR operand of v_fmac_f32) feeds two FMAs:
// halves the per-node s_load stream + issue overhead (the real limiter --
// VALUBusy is ~2x-inflated by the gfx94x formula; real VALU ~39%, kernel is
// stall-bound). Chunking + asm memory fences cap live ranges (no spill).
// ---------------------------------------------------------------------------
__global__ __launch_bounds__(BLK) void mlp_score_kernel(
    const float* __restrict__ x, const float* __restrict__ emb,
    const float* __restrict__ dag_h1, const float* __restrict__ glob_h1,
    const int* __restrict__ dag_ids, const int* __restrict__ obs_ids,
    const int* __restrict__ mask,
    const float* __restrict__ W1, const float* __restrict__ W2,
    const float* __restrict__ b2, const float* __restrict__ W3,
    const float* __restrict__ b3, const float* __restrict__ W4,
    const float* __restrict__ b4,
    float* __restrict__ scores, float* __restrict__ blk_m,
    double* __restrict__ blk_s, int N)
{
    const int base = blockIdx.x * (2 * BLK) + threadIdx.x;
    const int i0a = base;
    const int i0b = base + BLK;
    const bool va = (i0a < N);
    const bool vb = (i0b < N);
    const int ia = va ? i0a : (N - 1);
    const int ib = vb ? i0b : (N - 1);

    // --- ids first (gather addresses depend on them; latency hidden by x-phase) ---
    const int da = dag_ids[ia], db = dag_ids[ib];
    const int oa = obs_ids[ia], ob = obs_ids[ib];
    const int mka = mask[ia],  mkb = mask[ib];

    // --- x loads + x-phase: h1 init (k=0) + k=1..4, weights shared a/b ---
    const float* xra = x + (size_t)ia * 5;
    const float* xrb = x + (size_t)ib * 5;
    float xa0 = xra[0], xa1 = xra[1], xa2 = xra[2], xa3 = xra[3], xa4 = xra[4];
    float xb0 = xrb[0], xb1 = xrb[1], xb2 = xrb[2], xb3 = xrb[3], xb4 = xrb[4];

    float h1a[32], h1b[32];
#pragma unroll
    for (int j = 0; j < 32; j++) {
        const float w = W1[j];
        h1a[j] = xa0 * w;
        h1b[j] = xb0 * w;
    }
#pragma unroll
    for (int j = 0; j < 32; j++) {
        const float w = W1[32 + j];
        h1a[j] = fmaf(xa1, w, h1a[j]);
        h1b[j] = fmaf(xb1, w, h1b[j]);
    }
#pragma unroll
    for (int j = 0; j < 32; j++) {
        const float w = W1[64 + j];
        h1a[j] = fmaf(xa2, w, h1a[j]);
        h1b[j] = fmaf(xb2, w, h1b[j]);
    }
#pragma unroll
    for (int j = 0; j < 32; j++) {
        const float w = W1[96 + j];
        h1a[j] = fmaf(xa3, w, h1a[j]);
        h1b[j] = fmaf(xb3, w, h1b[j]);
    }
#pragma unroll
    for (int j = 0; j < 32; j++) {
        const float w = W1[128 + j];
        h1a[j] = fmaf(xa4, w, h1a[j]);
        h1b[j] = fmaf(xb4, w, h1b[j]);
    }

    // --- fold gathered per-segment partials, 4 fenced chunks (8 float4 each) ---
    // dag_h1 (2.5 MB) is L2-resident, glob_h1 (128 KB) L1/L2 -> short latency.
    const float4* dha = (const float4*)(dag_h1 + (size_t)da * 32);
    const float4* gha = (const float4*)(glob_h1 + (size_t)oa * 32);
    const float4* dhb = (const float4*)(dag_h1 + (size_t)db * 32);
    const float4* ghb = (const float4*)(glob_h1 + (size_t)ob * 32);

    fold2<0>(dha, gha, dhb, ghb, h1a, h1b);
    SCHED_FENCE();
    fold2<2>(dha, gha, dhb, ghb, h1a, h1b);
    SCHED_FENCE();
    fold2<4>(dha, gha, dhb, ghb, h1a, h1b);
    SCHED_FENCE();
    fold2<6>(dha, gha, dhb, ghb, h1a, h1b);
    SCHED_FENCE();

    // --- emb phase (k=5..36): 8 fenced chunks, 1-chunk prefetch ---
    const float4* era = (const float4*)(emb + (size_t)ia * 32);
    const float4* erb = (const float4*)(emb + (size_t)ib * 32);

    float4 pa = era[0], pb = erb[0];
    float4 na = pa, nb = pb;

    na = era[1]; nb = erb[1];
    emb_step<5>(pa, pb, W1, h1a, h1b);
    SCHED_FENCE();
    pa = na; pb = nb; na = era[2]; nb = erb[2];
    emb_step<9>(pa, pb, W1, h1a, h1b);
    SCHED_FENCE();
    pa = na; pb = nb; na = era[3]; nb = erb[3];
    emb_step<13>(pa, pb, W1, h1a, h1b);
    SCHED_FENCE();
    pa = na; pb = nb; na = era[4]; nb = erb[4];
    emb_step<17>(pa, pb, W1, h1a, h1b);
    SCHED_FENCE();
    pa = na; pb = nb; na = era[5]; nb = erb[5];
    emb_step<21>(pa, pb, W1, h1a, h1b);
    SCHED_FENCE();
    pa = na; pb = nb; na = era[6]; nb = erb[6];
    emb_step<25>(pa, pb, W1, h1a, h1b);
    SCHED_FENCE();
    pa = na; pb = nb; na = era[7]; nb = erb[7];
    emb_step<29>(pa, pb, W1, h1a, h1b);
    SCHED_FENCE();
    pa = na; pb = nb;
    emb_step<33>(pa, pb, W1, h1a, h1b);
    SCHED_FENCE();

#pragma unroll
    for (int j = 0; j < 32; j++) {
        h1a[j] = fmaxf(h1a[j], 0.f);
        h1b[j] = fmaxf(h1b[j], 0.f);
    }

    // --- layer 2: 32 -> 16 ---
    float h2a[16], h2b[16];
#pragma unroll
    for (int j = 0; j < 16; j++) { const float bb = b2[j]; h2a[j] = bb; h2b[j] = bb; }
#pragma unroll
    for (int k = 0; k < 32; k++) {
        const float vva = h1a[k];
        const float vvb = h1b[k];
#pragma unroll
        for (int j = 0; j < 16; j++) {
            const float w = W2[k * 16 + j];
            h2a[j] = fmaf(vva, w, h2a[j]);
            h2b[j] = fmaf(vvb, w, h2b[j]);
        }
    }
#pragma unroll
    for (int j = 0; j < 16; j++) {
        h2a[j] = fmaxf(h2a[j], 0.f);
        h2b[j] = fmaxf(h2b[j], 0.f);
    }

    // --- layer 3: 16 -> 8 ---
    float h3a[8], h3b[8];
#pragma unroll
    for (int j = 0; j < 8; j++) { const float bb = b3[j]; h3a[j] = bb; h3b[j] = bb; }
#pragma unroll
    for (int k = 0; k < 16; k++) {
        const float vva = h2a[k];
        const float vvb = h2b[k];
#pragma unroll
        for (int j = 0; j < 8; j++) {
            const float w = W3[k * 8 + j];
            h3a[j] = fmaf(vva, w, h3a[j]);
            h3b[j] = fmaf(vvb, w, h3b[j]);
        }
    }
#pragma unroll
    for (int j = 0; j < 8; j++) {
        h3a[j] = fmaxf(h3a[j], 0.f);
        h3b[j] = fmaxf(h3b[j], 0.f);
    }

    // --- layer 4 ---
    float sa = b4[0], sb = b4[0];
#pragma unroll
    for (int k = 0; k < 8; k++) {
        const float w = W4[k];
        sa = fmaf(h3a[k], w, sa);
        sb = fmaf(h3b[k], w, sb);
    }

    const bool livea = va && (mka != 0);
    const bool liveb = vb && (mkb != 0);
    if (va) scores[i0a] = livea ? sa : -FLT_MAX;
    if (vb) scores[i0b] = liveb ? sb : -FLT_MAX;

    // --- merge the thread's pair -> (m, s) ---
    float ma = livea ? sa : -INFINITY;
    float mb = liveb ? sb : -INFINITY;
    float m = fmaxf(ma, mb);
    double sd = 0.0;
    if (ma > -INFINITY) sd += (double)expf(ma - m);
    if (mb > -INFINITY) sd += (double)expf(mb - m);

    // --- wave shuffle reduce, then tiny LDS merge ---
#pragma unroll
    for (int off = 32; off > 0; off >>= 1) {
        float  mo = __shfl_down(m, off);
        double so = __shfl_down(sd, off);
        float M = fmaxf(m, mo);
        double out = 0.0;
        if (m  > -INFINITY) out += sd * (double)expf(m  - M);
        if (mo > -INFINITY) out += so * (double)expf(mo - M);
        m = M; sd = out;
    }
    __shared__ float  mw[BLK / 64];
    __shared__ double sw[BLK / 64];
    const int lane = threadIdx.x & 63, wid = threadIdx.x >> 6;
    if (lane == 0) { mw[wid] = m; sw[wid] = sd; }
    __syncthreads();
    if (threadIdx.x == 0) {
        float M = mw[0]; double S = sw[0];
#pragma unroll
        for (int w = 1; w < BLK / 64; w++) {
            float mbw = mw[w]; double sbw = sw[w];
            float Mn = fmaxf(M, mbw);
            double out = 0.0;
            if (M   > -INFINITY) out += S   * (double)expf(M   - Mn);
            if (mbw > -INFINITY) out += sbw * (double)expf(mbw - Mn);
            M = Mn; S = out;
        }
        blk_m[blockIdx.x] = M;
        blk_s[blockIdx.x] = S;
    }
}

// ---------------------------------------------------------------------------
// K4: merge per-block (m, s) pairs -> gmax, Z. One block.
// ---------------------------------------------------------------------------
__global__ __launch_bounds__(1024) void merge_kernel(
    const float* __restrict__ bm, const double* __restrict__ bs, int n,
    float* __restrict__ gmax, double* __restrict__ Z)
{
    float m = -INFINITY;
    double s = 0.0;
    for (int i = threadIdx.x; i < n; i += 1024) {
        float mb = bm[i]; double sb = bs[i];
        float M = fmaxf(m, mb);
        double out = 0.0;
        if (m  > -INFINITY) out += s  * (double)expf(m  - M);
        if (mb > -INFINITY) out += sb * (double)expf(mb - M);
        m = M; s = out;
    }
    __shared__ float  mred[1024];
    __shared__ double sred[1024];
    mred[threadIdx.x] = m;
    sred[threadIdx.x] = s;
    __syncthreads();
    for (int off = 512; off > 0; off >>= 1) {
        if (threadIdx.x < off) {
            float ma = mred[threadIdx.x], mb = mred[threadIdx.x + off];
            double sa = sred[threadIdx.x], sb = sred[threadIdx.x + off];
            float M = fmaxf(ma, mb);
            double out = 0.0;
            if (ma > -INFINITY) out += sa * (double)expf(ma - M);
            if (mb > -INFINITY) out += sb * (double)expf(mb - M);
            mred[threadIdx.x] = M;
            sred[threadIdx.x] = out;
        }
        __syncthreads();
    }
    if (threadIdx.x == 0) { *gmax = mred[0]; *Z = sred[0]; }
}

// ---------------------------------------------------------------------------
// K5: finalize out[i] = exp(s - gmax) / Z  (masked -FLT_MAX -> exactly 0).
// ---------------------------------------------------------------------------
__global__ __launch_bounds__(BLK) void finalize_kernel(
    const float* __restrict__ scores, int N,
    const float* __restrict__ gmaxp, const double* __restrict__ Zp,
    float* __restrict__ outp)
{
    const float gm = *gmaxp;
    const float rZ = (float)(1.0 / *Zp);
    int i = blockIdx.x * BLK + threadIdx.x;
    if (i < N) outp[i] = expf(scores[i] - gm) * rZ;
}

// ---------------------------------------------------------------------------
extern "C" void kernel_launch(void* const* d_in, const int* in_sizes, int n_in,
                              void* d_out, int out_size, void* d_ws, size_t ws_size,
                              hipStream_t stream)
{
    const float* x        = (const float*)d_in[0];
    const float* emb      = (const float*)d_in[1];
    const float* dag_sum  = (const float*)d_in[2];
    const float* glob_sum = (const float*)d_in[3];
    const int*   dag_cnt  = (const int*)d_in[4];
    const int*   obs_cnt  = (const int*)d_in[5];
    const int*   mask     = (const int*)d_in[6];   // bool staged as int32
    const float* W1 = (const float*)d_in[7];
    const float* b1 = (const float*)d_in[8];
    const float* W2 = (const float*)d_in[9];
    const float* b2 = (const float*)d_in[10];
    const float* W3 = (const float*)d_in[11];
    const float* b3 = (const float*)d_in[12];
    const float* W4 = (const float*)d_in[13];
    const float* b4 = (const float*)d_in[14];
    float* outp = (float*)d_out;

    const int N  = in_sizes[0] / 5;   // 2,000,000
    const int nd = in_sizes[4];       // 20,000
    const int no = in_sizes[5];       // 1,000

    const int main_blocks = (N + 2 * BLK - 1) / (2 * BLK);   // 3907

    // --- workspace layout (16B aligned slices) ---
    char* ws = (char*)d_ws;
    size_t off = 0;
    auto alloc = [&](size_t bytes) {
        void* p = ws + off;
        off += (bytes + 15) & ~(size_t)15;
        return p;
    };
    int*    dag_starts = (int*)   alloc((size_t)(nd + 1) * sizeof(int));
    int*    obs_starts = (int*)   alloc((size_t)(no + 1) * sizeof(int));
    int*    dag_ids    = (int*)   alloc((size_t)N * sizeof(int));
    int*    obs_ids    = (int*)   alloc((size_t)N * sizeof(int));
    float*  dag_h1     = (float*) alloc((size_t)nd * 32 * sizeof(float));
    float*  glob_h1    = (float*) alloc((size_t)no * 32 * sizeof(float));
    float*  scores     = (float*) alloc((size_t)N * sizeof(float));
    float*  blk_m      = (float*) alloc((size_t)main_blocks * sizeof(float));
    double* blk_s      = (double*)alloc((size_t)main_blocks * sizeof(double));
    float*  gmax       = (float*) alloc(sizeof(float));
    double* Z          = (double*)alloc(sizeof(double));
    (void)ws_size;

    // K0: prefix scans
    scan2_kernel<<<1, 1024, 0, stream>>>(dag_cnt, nd, obs_cnt, no, dag_starts, obs_starts);

    // K1: expand segment ids to nodes
    expand_ids_kernel<<<nd + no, 128, 0, stream>>>(dag_starts, nd, obs_starts, no, dag_ids, obs_ids);

    // K2: per-segment layer-1 partials
    {
        int total = (nd + no) * 32;
        seg_h1_kernel<<<(total + 255) / 256, 256, 0, stream>>>(
            dag_sum, nd, glob_sum, no, W1, b1, dag_h1, glob_h1);
    }

    // K3: main MLP + scores + per-block softmax partials (2 nodes/thread)
    mlp_score_kernel<<<main_blocks, BLK, 0, stream>>>(
        x, emb, dag_h1, glob_h1, dag_ids, obs_ids, mask,
        W1, W2, b2, W3, b3, W4, b4, scores, blk_m, blk_s, N);

    // K4: merge -> gmax, Z
    merge_kernel<<<1, 1024, 0, stream>>>(blk_m, blk_s, main_blocks, gmax, Z);

    // K5: finalize
    finalize_kernel<<<(N + BLK - 1) / BLK, BLK, 0, stream>>>(scores, N, gmax, Z, outp);
}

// Round 6
// 498.160 us; speedup vs baseline: 3.6999x; 3.6999x over previous
//
#include <hip/hip_runtime.h>
#include <math.h>
#include <float.h>

#define BLK 256

// ---------------------------------------------------------------------------
// K0: fast exclusive scan of both count arrays. One block, 1024 threads.
// ---------------------------------------------------------------------------
__device__ __forceinline__ void scan_one(const int* __restrict__ cnt, int n,
                                         int* __restrict__ starts, int* wsum)
{
    const int t = threadIdx.x;
    const int chunk = (n + 1023) / 1024;
    const int base = t * chunk;

    int sum = 0;
    for (int k = 0; k < chunk; k++) {
        int idx = base + k;
        if (idx < n) sum += cnt[idx];
    }

    const int lane = t & 63, wid = t >> 6;
    int v = sum;
#pragma unroll
    for (int off = 1; off < 64; off <<= 1) {
        int y = __shfl_up(v, off);
        if (lane >= off) v += y;
    }
    if (lane == 63) wsum[wid] = v;
    __syncthreads();
    if (wid == 0) {
        int w = (lane < 16) ? wsum[lane] : 0;
#pragma unroll
        for (int off = 1; off < 16; off <<= 1) {
            int y = __shfl_up(w, off);
            if (lane >= off) w += y;
        }
        if (lane < 16) wsum[lane] = w;
    }
    __syncthreads();

    int thr_excl = ((wid > 0) ? wsum[wid - 1] : 0) + v - sum;
    int run = thr_excl;
    for (int k = 0; k < chunk; k++) {
        int idx = base + k;
        if (idx < n) { starts[idx] = run; run += cnt[idx]; }
    }
    if (t == 0) starts[n] = wsum[15];
    __syncthreads();
}

__global__ __launch_bounds__(1024) void scan2_kernel(
    const int* __restrict__ dag_cnt, int nd,
    const int* __restrict__ obs_cnt, int no,
    int* __restrict__ dag_starts, int* __restrict__ obs_starts)
{
    __shared__ int wsum[16];
    scan_one(dag_cnt, nd, dag_starts, wsum);
    scan_one(obs_cnt, no, obs_starts, wsum);
}

// ---------------------------------------------------------------------------
// K1: expand segment ids to per-node arrays (one block per segment).
// ---------------------------------------------------------------------------
__global__ __launch_bounds__(128) void expand_ids_kernel(
    const int* __restrict__ dag_starts, int nd,
    const int* __restrict__ obs_starts, int no,
    int* __restrict__ dag_ids, int* __restrict__ obs_ids)
{
    int seg = blockIdx.x;
    if (seg < nd) {
        int s = dag_starts[seg], e = dag_starts[seg + 1];
        for (int i = s + threadIdx.x; i < e; i += 128) dag_ids[i] = seg;
    } else {
        int g = seg - nd;
        int s = obs_starts[g], e = obs_starts[g + 1];
        for (int i = s + threadIdx.x; i < e; i += 128) obs_ids[i] = g;
    }
}

// ---------------------------------------------------------------------------
// K2: per-segment layer-1 partials (dag rows 37..68 no bias; glob rows 69..100 +b1).
// ---------------------------------------------------------------------------
__global__ __launch_bounds__(256) void seg_h1_kernel(
    const float* __restrict__ dag_sum, int nd,
    const float* __restrict__ glob_sum, int no,
    const float* __restrict__ W1, const float* __restrict__ b1,
    float* __restrict__ dag_h1, float* __restrict__ glob_h1)
{
    __shared__ float Wd[32 * 32];
    __shared__ float Wg[32 * 32];
    for (int t = threadIdx.x; t < 32 * 32; t += 256) {
        int k = t / 32, j = t % 32;
        Wd[t] = W1[(size_t)(37 + k) * 32 + j];
        Wg[t] = W1[(size_t)(69 + k) * 32 + j];
    }
    __syncthreads();

    int gid = blockIdx.x * 256 + threadIdx.x;
    int seg = gid / 32;
    int j   = gid % 32;
    if (seg >= nd + no) return;

    const float* srow;
    const float* Wl;
    float acc;
    float* outp;
    if (seg < nd) {
        srow = dag_sum + (size_t)seg * 32;
        Wl = Wd; acc = 0.f;
        outp = dag_h1 + (size_t)seg * 32 + j;
    } else {
        srow = glob_sum + (size_t)(seg - nd) * 32;
        Wl = Wg; acc = b1[j];
        outp = glob_h1 + (size_t)(seg - nd) * 32 + j;
    }
#pragma unroll
    for (int k = 0; k < 32; k++)
        acc = fmaf(srow[k], Wl[k * 32 + j], acc);
    *outp = acc;
}

// ---------------------------------------------------------------------------
// K3: main MLP. ONE node per thread (round-1 structure, measured 154 us).
// Pipe-split weight delivery:
//   - Layer 1 (1184 floats, the big stream): scalar path (s_load -> SGPR
//     operand of v_fmac_f32). Round 1 proved this beats LDS for the bulk.
//   - Layers 2-4 + biases (~2.7 KB): staged in LDS, read as uniform-address
//     broadcast ds_read. Moves ~170 b128-reads/wave onto the DS pipe (idle
//     in round 1; saturated only at round-0's 456 reads/wave) and removes
//     the LATE scalar-wait chokepoints where no other work hides them.
// Round 2-5 lesson: 2 nodes/thread is dead (unfenced spills 133MB scratch;
// fenced serializes 10x). No fences here.
// ---------------------------------------------------------------------------
__global__ __launch_bounds__(BLK) void mlp_score_kernel(
    const float* __restrict__ x, const float* __restrict__ emb,
    const float* __restrict__ dag_h1, const float* __restrict__ glob_h1,
    const int* __restrict__ dag_ids, const int* __restrict__ obs_ids,
    const int* __restrict__ mask,
    const float* __restrict__ W1, const float* __restrict__ W2,
    const float* __restrict__ b2, const float* __restrict__ W3,
    const float* __restrict__ b3, const float* __restrict__ W4,
    const float* __restrict__ b4,
    float* __restrict__ scores, float* __restrict__ blk_m,
    double* __restrict__ blk_s, int N)
{
    __shared__ float W2l[32 * 16];
    __shared__ float W3l[16 * 8];
    __shared__ float Cst[33];   // [0:16)=b2, [16:24)=b3, [24:32)=W4, [32]=b4

    const int i0 = blockIdx.x * BLK + threadIdx.x;
    const bool valid = (i0 < N);
    const int i = valid ? i0 : (N - 1);   // clamp: loads safe, result discarded

    // --- per-node loads: ids first (gathers depend on them) ---
    const int d  = dag_ids[i];
    const int o  = obs_ids[i];
    const int mk = mask[i];

    // --- issue gathers (consumed at h1 init; staging below overlaps latency) ---
    const float4* dh = (const float4*)(dag_h1 + (size_t)d * 32);
    const float4* gh = (const float4*)(glob_h1 + (size_t)o * 32);
    float4 dq0 = dh[0], dq1 = dh[1], dq2 = dh[2], dq3 = dh[3],
           dq4 = dh[4], dq5 = dh[5], dq6 = dh[6], dq7 = dh[7];
    float4 gq0 = gh[0], gq1 = gh[1], gq2 = gh[2], gq3 = gh[3],
           gq4 = gh[4], gq5 = gh[5], gq6 = gh[6], gq7 = gh[7];

    // --- x loads ---
    const float* xr = x + (size_t)i * 5;
    float xv0 = xr[0], xv1 = xr[1], xv2 = xr[2], xv3 = xr[3], xv4 = xr[4];
    const float4* er = (const float4*)(emb + (size_t)i * 32);

    // --- stage small late-layer weights to LDS (overlaps gather latency) ---
    for (int t = threadIdx.x; t < 32 * 16; t += BLK) W2l[t] = W2[t];
    for (int t = threadIdx.x; t < 16 * 8;  t += BLK) W3l[t] = W3[t];
    if (threadIdx.x < 16)      Cst[threadIdx.x] = b2[threadIdx.x];
    else if (threadIdx.x < 24) Cst[threadIdx.x] = b3[threadIdx.x - 16];
    else if (threadIdx.x < 32) Cst[threadIdx.x] = W4[threadIdx.x - 24];
    else if (threadIdx.x == 32) Cst[32] = b4[0];
    __syncthreads();

    // --- layer 1: init from gathered per-segment partials (b1 inside glob_h1) ---
    float h1[32];
#pragma unroll
    for (int c = 0; c < 4; c++) {
        h1[0  + c] = ((const float*)&dq0)[c] + ((const float*)&gq0)[c];
        h1[4  + c] = ((const float*)&dq1)[c] + ((const float*)&gq1)[c];
        h1[8  + c] = ((const float*)&dq2)[c] + ((const float*)&gq2)[c];
        h1[12 + c] = ((const float*)&dq3)[c] + ((const float*)&gq3)[c];
        h1[16 + c] = ((const float*)&dq4)[c] + ((const float*)&gq4)[c];
        h1[20 + c] = ((const float*)&dq5)[c] + ((const float*)&gq5)[c];
        h1[24 + c] = ((const float*)&dq6)[c] + ((const float*)&gq6)[c];
        h1[28 + c] = ((const float*)&dq7)[c] + ((const float*)&gq7)[c];
    }

    // --- layer 1: x phase (weights from global = s_load, SGPR operand) ---
#pragma unroll
    for (int j = 0; j < 32; j++) h1[j] = fmaf(xv0, W1[j], h1[j]);
#pragma unroll
    for (int j = 0; j < 32; j++) h1[j] = fmaf(xv1, W1[32 + j], h1[j]);
#pragma unroll
    for (int j = 0; j < 32; j++) h1[j] = fmaf(xv2, W1[64 + j], h1[j]);
#pragma unroll
    for (int j = 0; j < 32; j++) h1[j] = fmaf(xv3, W1[96 + j], h1[j]);
#pragma unroll
    for (int j = 0; j < 32; j++) h1[j] = fmaf(xv4, W1[128 + j], h1[j]);

    // --- layer 1: emb phase (k = 5..36, scalar weights) ---
#pragma unroll
    for (int q = 0; q < 8; q++) {
        float4 e = er[q];
#pragma unroll
        for (int kk = 0; kk < 4; kk++) {
            const int k = 5 + q * 4 + kk;
            const float v = (kk == 0) ? e.x : (kk == 1) ? e.y : (kk == 2) ? e.z : e.w;
#pragma unroll
            for (int j = 0; j < 32; j++)
                h1[j] = fmaf(v, W1[k * 32 + j], h1[j]);
        }
    }
#pragma unroll
    for (int j = 0; j < 32; j++) h1[j] = fmaxf(h1[j], 0.f);

    // --- layer 2: 32 -> 16 (weights from LDS broadcast) ---
    float h2[16];
#pragma unroll
    for (int j = 0; j < 16; j++) h2[j] = Cst[j];
#pragma unroll
    for (int k = 0; k < 32; k++) {
        const float v = h1[k];
#pragma unroll
        for (int j = 0; j < 16; j++)
            h2[j] = fmaf(v, W2l[k * 16 + j], h2[j]);
    }
#pragma unroll
    for (int j = 0; j < 16; j++) h2[j] = fmaxf(h2[j], 0.f);

    // --- layer 3: 16 -> 8 (LDS) ---
    float h3[8];
#pragma unroll
    for (int j = 0; j < 8; j++) h3[j] = Cst[16 + j];
#pragma unroll
    for (int k = 0; k < 16; k++) {
        const float v = h2[k];
#pragma unroll
        for (int j = 0; j < 8; j++)
            h3[j] = fmaf(v, W3l[k * 8 + j], h3[j]);
    }
#pragma unroll
    for (int j = 0; j < 8; j++) h3[j] = fmaxf(h3[j], 0.f);

    // --- layer 4 (LDS) ---
    float s = Cst[32];
#pragma unroll
    for (int k = 0; k < 8; k++) s = fmaf(h3[k], Cst[24 + k], s);

    const bool live = valid && (mk != 0);
    if (valid) scores[i0] = live ? s : -FLT_MAX;

    // --- block (m, sum) merge: wave shuffle reduce, then tiny LDS merge ---
    float  m  = live ? s : -INFINITY;
    double sd = live ? 1.0 : 0.0;
#pragma unroll
    for (int off = 32; off > 0; off >>= 1) {
        float  mo = __shfl_down(m, off);
        double so = __shfl_down(sd, off);
        float M = fmaxf(m, mo);
        double out = 0.0;
        if (m  > -INFINITY) out += sd * (double)expf(m  - M);
        if (mo > -INFINITY) out += so * (double)expf(mo - M);
        m = M; sd = out;
    }
    __shared__ float  mw[BLK / 64];
    __shared__ double sw[BLK / 64];
    const int lane = threadIdx.x & 63, wid = threadIdx.x >> 6;
    if (lane == 0) { mw[wid] = m; sw[wid] = sd; }
    __syncthreads();
    if (threadIdx.x == 0) {
        float M = mw[0]; double S = sw[0];
#pragma unroll
        for (int w = 1; w < BLK / 64; w++) {
            float mb = mw[w]; double sb = sw[w];
            float Mn = fmaxf(M, mb);
            double out = 0.0;
            if (M  > -INFINITY) out += S  * (double)expf(M  - Mn);
            if (mb > -INFINITY) out += sb * (double)expf(mb - Mn);
            M = Mn; S = out;
        }
        blk_m[blockIdx.x] = M;
        blk_s[blockIdx.x] = S;
    }
}

// ---------------------------------------------------------------------------
// K4: merge per-block (m, s) pairs -> gmax, Z. One block.
// ---------------------------------------------------------------------------
__global__ __launch_bounds__(1024) void merge_kernel(
    const float* __restrict__ bm, const double* __restrict__ bs, int n,
    float* __restrict__ gmax, double* __restrict__ Z)
{
    float m = -INFINITY;
    double s = 0.0;
    for (int i = threadIdx.x; i < n; i += 1024) {
        float mb = bm[i]; double sb = bs[i];
        float M = fmaxf(m, mb);
        double out = 0.0;
        if (m  > -INFINITY) out += s  * (double)expf(m  - M);
        if (mb > -INFINITY) out += sb * (double)expf(mb - M);
        m = M; s = out;
    }
    __shared__ float  mred[1024];
    __shared__ double sred[1024];
    mred[threadIdx.x] = m;
    sred[threadIdx.x] = s;
    __syncthreads();
    for (int off = 512; off > 0; off >>= 1) {
        if (threadIdx.x < off) {
            float ma = mred[threadIdx.x], mb = mred[threadIdx.x + off];
            double sa = sred[threadIdx.x], sb = sred[threadIdx.x + off];
            float M = fmaxf(ma, mb);
            double out = 0.0;
            if (ma > -INFINITY) out += sa * (double)expf(ma - M);
            if (mb > -INFINITY) out += sb * (double)expf(mb - M);
            mred[threadIdx.x] = M;
            sred[threadIdx.x] = out;
        }
        __syncthreads();
    }
    if (threadIdx.x == 0) { *gmax = mred[0]; *Z = sred[0]; }
}

// ---------------------------------------------------------------------------
// K5: finalize out[i] = exp(s - gmax) / Z  (masked -FLT_MAX -> exactly 0).
// ---------------------------------------------------------------------------
__global__ __launch_bounds__(BLK) void finalize_kernel(
    const float* __restrict__ scores, int N,
    const float* __restrict__ gmaxp, const double* __restrict__ Zp,
    float* __restrict__ outp)
{
    const float gm = *gmaxp;
    const float rZ = (float)(1.0 / *Zp);
    int i = blockIdx.x * BLK + threadIdx.x;
    if (i < N) outp[i] = expf(scores[i] - gm) * rZ;
}

// ---------------------------------------------------------------------------
extern "C" void kernel_launch(void* const* d_in, const int* in_sizes, int n_in,
                              void* d_out, int out_size, void* d_ws, size_t ws_size,
                              hipStream_t stream)
{
    const float* x        = (const float*)d_in[0];
    const float* emb      = (const float*)d_in[1];
    const float* dag_sum  = (const float*)d_in[2];
    const float* glob_sum = (const float*)d_in[3];
    const int*   dag_cnt  = (const int*)d_in[4];
    const int*   obs_cnt  = (const int*)d_in[5];
    const int*   mask     = (const int*)d_in[6];   // bool staged as int32
    const float* W1 = (const float*)d_in[7];
    const float* b1 = (const float*)d_in[8];
    const float* W2 = (const float*)d_in[9];
    const float* b2 = (const float*)d_in[10];
    const float* W3 = (const float*)d_in[11];
    const float* b3 = (const float*)d_in[12];
    const float* W4 = (const float*)d_in[13];
    const float* b4 = (const float*)d_in[14];
    float* outp = (float*)d_out;

    const int N  = in_sizes[0] / 5;   // 2,000,000
    const int nd = in_sizes[4];       // 20,000
    const int no = in_sizes[5];       // 1,000

    const int main_blocks = (N + BLK - 1) / BLK;   // 7813

    // --- workspace layout (16B aligned slices) ---
    char* ws = (char*)d_ws;
    size_t off = 0;
    auto alloc = [&](size_t bytes) {
        void* p = ws + off;
        off += (bytes + 15) & ~(size_t)15;
        return p;
    };
    int*    dag_starts = (int*)   alloc((size_t)(nd + 1) * sizeof(int));
    int*    obs_starts = (int*)   alloc((size_t)(no + 1) * sizeof(int));
    int*    dag_ids    = (int*)   alloc((size_t)N * sizeof(int));
    int*    obs_ids    = (int*)   alloc((size_t)N * sizeof(int));
    float*  dag_h1     = (float*) alloc((size_t)nd * 32 * sizeof(float));
    float*  glob_h1    = (float*) alloc((size_t)no * 32 * sizeof(float));
    float*  scores     = (float*) alloc((size_t)N * sizeof(float));
    float*  blk_m      = (float*) alloc((size_t)main_blocks * sizeof(float));
    double* blk_s      = (double*)alloc((size_t)main_blocks * sizeof(double));
    float*  gmax       = (float*) alloc(sizeof(float));
    double* Z          = (double*)alloc(sizeof(double));
    (void)ws_size;

    // K0: prefix scans
    scan2_kernel<<<1, 1024, 0, stream>>>(dag_cnt, nd, obs_cnt, no, dag_starts, obs_starts);

    // K1: expand segment ids to nodes
    expand_ids_kernel<<<nd + no, 128, 0, stream>>>(dag_starts, nd, obs_starts, no, dag_ids, obs_ids);

    // K2: per-segment layer-1 partials
    {
        int total = (nd + no) * 32;
        seg_h1_kernel<<<(total + 255) / 256, 256, 0, stream>>>(
            dag_sum, nd, glob_sum, no, W1, b1, dag_h1, glob_h1);
    }

    // K3: main MLP + scores + per-block softmax partials
    mlp_score_kernel<<<main_blocks, BLK, 0, stream>>>(
        x, emb, dag_h1, glob_h1, dag_ids, obs_ids, mask,
        W1, W2, b2, W3, b3, W4, b4, scores, blk_m, blk_s, N);

    // K4: merge -> gmax, Z
    merge_kernel<<<1, 1024, 0, stream>>>(blk_m, blk_s, main_blocks, gmax, Z);

    // K5: finalize
    finalize_kernel<<<(N + BLK - 1) / BLK, BLK, 0, stream>>>(scores, N, gmax, Z, outp);
}